// Round 11
// baseline (405.549 us; speedup 1.0000x reference)
//
#include <hip/hip_runtime.h>

#define NN 100000
#define EE 1600000
#define NPAD 100032          // NN rounded up to 64-row MFMA tiles
#define NBKT 196             // ceil(NN/512) scatter buckets
#define CAP 9216             // bucket capacity (mean 8192, sigma 90 -> 11 sigma)
#define MBLK 392             // fused-mlp blocks (392*256 rows >= NN; 2/CU co-resident)
#define BN_EPS 1e-5f

using f32x4  = __attribute__((ext_vector_type(4))) float;
using f32x8  = __attribute__((ext_vector_type(8))) float;
using s16x8  = __attribute__((ext_vector_type(8))) short;
using u16x4  = __attribute__((ext_vector_type(4))) unsigned short;
using u16x8  = __attribute__((ext_vector_type(8))) unsigned short;
using bf16x8 = __attribute__((ext_vector_type(8))) __bf16;
typedef unsigned short ushort_t;

__device__ __forceinline__ float bf2f(ushort_t b) {
  union { unsigned u; float f; } x; x.u = ((unsigned)b) << 16; return x.f;
}
__device__ __forceinline__ ushort_t f2bf(float f) {
  union { float f; unsigned u; } x; x.f = f;
  unsigned r = x.u + 0x7fffu + ((x.u >> 16) & 1u);   // RN-even; no NaNs in pipeline
  return (ushort_t)(r >> 16);
}

// -------- merged k_bin + k_prep: blocks 0..781 bin (8 edges/thr),
//          782..7031 x->bf16, 7032..7044 W swizzle --------
__global__ __launch_bounds__(256) void k_binprep(
    const int* __restrict__ src, const int* __restrict__ dst,
    int* __restrict__ gbc, unsigned* __restrict__ ebuf,
    const float* __restrict__ x, ushort_t* __restrict__ hb,
    const float* __restrict__ W1s, const float* __restrict__ W2s,
    ushort_t* __restrict__ wf) {
  __shared__ int hist[NBKT];
  int b = blockIdx.x, t = threadIdx.x;
  if (b < 782) {
    for (int i = t; i < NBKT; i += 256) hist[i] = 0;
    __syncthreads();
    int base = b * 2048;
    int s[8], d[8];
#pragma unroll
    for (int j = 0; j < 8; j++) {
      int e = base + j * 256 + t;
      if (e < EE) { s[j] = src[e]; d[j] = dst[e]; atomicAdd(&hist[d[j] >> 9], 1); }
      else d[j] = -1;
    }
    __syncthreads();
    for (int i = t; i < NBKT; i += 256) {
      int c = hist[i];
      hist[i] = c ? atomicAdd(&gbc[i], c) : 0;   // reserve in-bucket run
    }
    __syncthreads();
#pragma unroll
    for (int j = 0; j < 8; j++) {
      if (d[j] >= 0) {
        int bkt = d[j] >> 9;
        int pos = atomicAdd(&hist[bkt], 1);
        if (pos < CAP)
          ebuf[(size_t)bkt * CAP + pos] = (unsigned)s[j] | ((unsigned)(d[j] & 511) << 17);
      }
    }
  } else if (b < 7032) {
    int i = (b - 782) * 256 + t;      // 4 elems of x each
    f32x4 v = *(const f32x4*)(x + (size_t)i * 4);
    u16x4 o;
#pragma unroll
    for (int m = 0; m < 4; m++) o[m] = f2bf(v[m]);
    *(u16x4*)(hb + (size_t)i * 4) = o;
  } else {
    int gid = (b - 7032) * 256 + t;
    if (gid >= 3072) return;          // 6 mats * 2u * 4t * 64 lanes
    int mat = gid >> 9, rem = gid & 511;
    int u = rem >> 8, tt = (rem >> 6) & 3, lane = rem & 63;
    const float* W = ((mat & 1) ? W2s : W1s) + (mat >> 1) * 4096;
    ushort_t* o = wf + gid * 8;
#pragma unroll
    for (int j = 0; j < 8; j++) {
      int k = u * 32 + (lane >> 4) * 8 + j;
      int n = tt * 16 + (lane & 15);
      o[j] = f2bf(W[k * 64 + n]);
    }
  }
}

// scan bucket counts -> ebase; rowptr[NN]=EE; zero barrier counters
__global__ void k_bktscan(const int* __restrict__ gbc, int* __restrict__ ebase,
                          int* __restrict__ rowptr, int* __restrict__ bar) {
  __shared__ int sd[256];
  int t = threadIdx.x;
  if (t < 8) bar[t] = 0;                       // per-layer barrier counters
  int c = (t < NBKT) ? min(gbc[t], CAP) : 0;
  sd[t] = c; __syncthreads();
  for (int off = 1; off < 256; off <<= 1) {
    int x = 0;
    if (t >= off) x = sd[t - off];
    __syncthreads();
    sd[t] += x;
    __syncthreads();
  }
  if (t < NBKT) ebase[t] = sd[t] - c;          // exclusive
  if (t == NBKT - 1) rowptr[NN] = sd[t];       // == EE
}

// per bucket: LDS degree hist -> scan -> rowptr + fine scatter (1024 thr).
__global__ __launch_bounds__(1024) void k_fine(const unsigned* __restrict__ ebuf,
                                               const int* __restrict__ gbc,
                                               const int* __restrict__ ebase,
                                               int* __restrict__ rowptr,
                                               int* __restrict__ csr) {
  __shared__ int dcur[512];
  __shared__ int sd[256];
  int b = blockIdx.x, t = threadIdx.x;
  int cnt = min(gbc[b], CAP);
  int eb = ebase[b];
  const unsigned* eb_p = ebuf + (size_t)b * CAP;
  if (t < 512) dcur[t] = 0;
  __syncthreads();
  for (int e = t; e < cnt; e += 1024)
    atomicAdd(&dcur[(eb_p[e] >> 17) & 511], 1);
  __syncthreads();
  int a0 = 0, a1 = 0, ps = 0;
  if (t < 256) { a0 = dcur[2 * t]; a1 = dcur[2 * t + 1]; ps = a0 + a1; sd[t] = ps; }
  __syncthreads();
  for (int off = 1; off < 256; off <<= 1) {
    int x = 0;
    if (t < 256 && t >= off) x = sd[t - off];
    __syncthreads();
    if (t < 256) sd[t] += x;
    __syncthreads();
  }
  if (t < 256) {
    int g0 = eb + sd[t] - ps;                  // global csr start for local node 2t
    dcur[2 * t] = g0; dcur[2 * t + 1] = g0 + a0;
    int n = (b << 9) + 2 * t;
    if (n < NN) rowptr[n] = g0;
    if (n + 1 < NN) rowptr[n + 1] = g0 + a0;
  }
  __syncthreads();
  for (int e = t; e < cnt; e += 1024) {
    unsigned v = eb_p[e];
    int pos = atomicAdd(&dcur[(v >> 17) & 511], 1);
    csr[pos] = (int)(v & 0x1FFFFu);
  }
}

// ---------------- k_gat: lean barrier-free gather (proven R8/R9 shape) -------
__global__ __launch_bounds__(256) void k_gat(
    const ushort_t* __restrict__ hb, const int* __restrict__ rowptr,
    const int* __restrict__ csr, ushort_t* __restrict__ aggb) {
  int tid = threadIdx.x;
  int grp = tid >> 3, fl = tid & 7;
  int node = blockIdx.x * 32 + grp;            // grid 3125*32 == NN exactly
  if (node >= NN) return;
  const ushort_t* hbase = hb + fl * 8;
  f32x8 A;
  {
    u16x8 sr = *(const u16x8*)(hbase + (size_t)node * 64);
#pragma unroll
    for (int m = 0; m < 8; m++) A[m] = bf2f(sr[m]);
  }
  int e = rowptr[node];
  int rem = rowptr[node + 1] - e;
  if (rem >= 8) {
    int s0 = csr[e],     s1 = csr[e + 1], s2 = csr[e + 2], s3 = csr[e + 3];
    int s4 = csr[e + 4], s5 = csr[e + 5], s6 = csr[e + 6], s7 = csr[e + 7];
    for (;;) {
      u16x8 r0 = *(const u16x8*)(hbase + (size_t)s0 * 64);
      u16x8 r1 = *(const u16x8*)(hbase + (size_t)s1 * 64);
      u16x8 r2 = *(const u16x8*)(hbase + (size_t)s2 * 64);
      u16x8 r3 = *(const u16x8*)(hbase + (size_t)s3 * 64);
      u16x8 r4 = *(const u16x8*)(hbase + (size_t)s4 * 64);
      u16x8 r5 = *(const u16x8*)(hbase + (size_t)s5 * 64);
      u16x8 r6 = *(const u16x8*)(hbase + (size_t)s6 * 64);
      u16x8 r7 = *(const u16x8*)(hbase + (size_t)s7 * 64);
      e += 8; rem -= 8;
      bool more = (rem >= 8);
      if (more) {                              // prefetch next chunk's indices
        s0 = csr[e];     s1 = csr[e + 1]; s2 = csr[e + 2]; s3 = csr[e + 3];
        s4 = csr[e + 4]; s5 = csr[e + 5]; s6 = csr[e + 6]; s7 = csr[e + 7];
      }
#pragma unroll
      for (int m = 0; m < 8; m++) A[m] += bf2f(r0[m]);
#pragma unroll
      for (int m = 0; m < 8; m++) A[m] += bf2f(r1[m]);
#pragma unroll
      for (int m = 0; m < 8; m++) A[m] += bf2f(r2[m]);
#pragma unroll
      for (int m = 0; m < 8; m++) A[m] += bf2f(r3[m]);
#pragma unroll
      for (int m = 0; m < 8; m++) A[m] += bf2f(r4[m]);
#pragma unroll
      for (int m = 0; m < 8; m++) A[m] += bf2f(r5[m]);
#pragma unroll
      for (int m = 0; m < 8; m++) A[m] += bf2f(r6[m]);
#pragma unroll
      for (int m = 0; m < 8; m++) A[m] += bf2f(r7[m]);
      if (!more) break;
    }
  }
  if (rem > 0) {                               // clamp-masked tail (exact)
    int last = e + rem - 1;
    int s0 = csr[e];
    int s1 = csr[min(e + 1, last)], s2 = csr[min(e + 2, last)];
    int s3 = csr[min(e + 3, last)], s4 = csr[min(e + 4, last)];
    int s5 = csr[min(e + 5, last)], s6 = csr[min(e + 6, last)];
    int s7 = csr[min(e + 7, last)];
    u16x8 r0 = *(const u16x8*)(hbase + (size_t)s0 * 64);
    u16x8 r1 = *(const u16x8*)(hbase + (size_t)s1 * 64);
    u16x8 r2 = *(const u16x8*)(hbase + (size_t)s2 * 64);
    u16x8 r3 = *(const u16x8*)(hbase + (size_t)s3 * 64);
    u16x8 r4 = *(const u16x8*)(hbase + (size_t)s4 * 64);
    u16x8 r5 = *(const u16x8*)(hbase + (size_t)s5 * 64);
    u16x8 r6 = *(const u16x8*)(hbase + (size_t)s6 * 64);
    u16x8 r7 = *(const u16x8*)(hbase + (size_t)s7 * 64);
    float w1 = (rem > 1) ? 1.f : 0.f, w2 = (rem > 2) ? 1.f : 0.f;
    float w3 = (rem > 3) ? 1.f : 0.f, w4 = (rem > 4) ? 1.f : 0.f;
    float w5 = (rem > 5) ? 1.f : 0.f, w6 = (rem > 6) ? 1.f : 0.f;
    float w7 = (rem > 7) ? 1.f : 0.f;
#pragma unroll
    for (int m = 0; m < 8; m++) A[m] += bf2f(r0[m]);
#pragma unroll
    for (int m = 0; m < 8; m++) A[m] += w1 * bf2f(r1[m]);
#pragma unroll
    for (int m = 0; m < 8; m++) A[m] += w2 * bf2f(r2[m]);
#pragma unroll
    for (int m = 0; m < 8; m++) A[m] += w3 * bf2f(r3[m]);
#pragma unroll
    for (int m = 0; m < 8; m++) A[m] += w4 * bf2f(r4[m]);
#pragma unroll
    for (int m = 0; m < 8; m++) A[m] += w5 * bf2f(r5[m]);
#pragma unroll
    for (int m = 0; m < 8; m++) A[m] += w6 * bf2f(r6[m]);
#pragma unroll
    for (int m = 0; m < 8; m++) A[m] += w7 * bf2f(r7[m]);
  }
  u16x8 o;
#pragma unroll
  for (int m = 0; m < 8; m++) o[m] = f2bf(A[m]);
  *(u16x8*)(aggb + (size_t)node * 64 + fl * 8) = o;     // 128B/group coalesced
}

// ---------------- k_mlp (fused): mlp1 + device barrier + mlp2 ----------------
// 392 blocks x 256 thr x 256 rows; PLAIN launch + hand-rolled barrier.
// Co-residency guaranteed by resources: LDS 56.5KB -> 2 blocks/CU -> 512
// slots >= 392 (serial stream, nothing else resident). z lives in LDS across
// the barrier (no zb round-trip). All LDS rows are WAVE-PRIVATE (stager
// tid>>2, MFMA row wv*16+lo, z-writer wv*16+quad*4+r in wave wv's 16-row
// span). Stats: per-block partials to DISTINCT pstats lines (agent scope);
// release via ACQ_REL counter add; ACQUIRE spin; atomic loads after.
__global__ __launch_bounds__(256) void k_mlp(
    const ushort_t* __restrict__ aggb, ushort_t* __restrict__ hb,
    float* __restrict__ out, const ushort_t* __restrict__ wf1,
    const ushort_t* __restrict__ wf2, const float* __restrict__ b1,
    const float* __restrict__ b2, const float* __restrict__ gam,
    const float* __restrict__ bet, float* __restrict__ pstats,
    int* __restrict__ bar,
    const float* __restrict__ Wd, const float* __restrict__ bd,
    int relu_out) {
  __shared__ __align__(16) ushort_t zl[4][64 * 72];     // 36.9 KB (agg->z in place)
  __shared__ __align__(16) float swf[64 * 68];          // 17.4 KB (swb aliases)
  __shared__ float lsum[64], lsq[64], red[256], abn[64], cbn[64];
  ushort_t* swb = (ushort_t*)swf;
  int tid = threadIdx.x;
  int wv = tid >> 6, lane = tid & 63;
  int quad = lane >> 4, lo = lane & 15;
  int rr = tid >> 2, c0 = (tid & 3) * 16;
  int blk = blockIdx.x;
  if (tid < 64) { lsum[tid] = 0.f; lsq[tid] = 0.f; }

  // ---- stage 4 tiles (wave-private rows) ----
#pragma unroll
  for (int it = 0; it < 4; it++) {
    size_t grow = (size_t)blk * 256 + it * 64 + rr;
    u16x8 v0 = {0, 0, 0, 0, 0, 0, 0, 0}, v1 = v0;
    if (grow < NN) {
      v0 = *(const u16x8*)(aggb + grow * 64 + c0);
      v1 = *(const u16x8*)(aggb + grow * 64 + c0 + 8);
    }
    *(u16x8*)(zl[it] + rr * 72 + c0) = v0;
    *(u16x8*)(zl[it] + rr * 72 + c0 + 8) = v1;
  }

  // ---- phase A: z = agg@W1 + b1, in place; stats in regs ----
  float s1a[4] = {0.f, 0.f, 0.f, 0.f}, s2a[4] = {0.f, 0.f, 0.f, 0.f};
  {
    s16x8 bfr[2][4];
#pragma unroll
    for (int u = 0; u < 2; u++)
#pragma unroll
      for (int t = 0; t < 4; t++)
        bfr[u][t] = *(const s16x8*)(wf1 + (size_t)((u * 4 + t) * 64 + lane) * 8);
    float bbv[4];
#pragma unroll
    for (int t = 0; t < 4; t++) bbv[t] = b1[t * 16 + lo];
#pragma unroll
    for (int it = 0; it < 4; it++) {
      f32x4 acc[4] = {};
#pragma unroll
      for (int u = 0; u < 2; u++) {
        bf16x8 af = *(const bf16x8*)(zl[it] + (wv * 16 + lo) * 72 + u * 32 + quad * 8);
#pragma unroll
        for (int t = 0; t < 4; t++)
          acc[t] = __builtin_amdgcn_mfma_f32_16x16x32_bf16(
              af, __builtin_bit_cast(bf16x8, bfr[u][t]), acc[t], 0, 0, 0);
      }
      int row0 = blk * 256 + it * 64 + wv * 16;
#pragma unroll
      for (int t = 0; t < 4; t++) {
        int col = t * 16 + lo;
#pragma unroll
        for (int r = 0; r < 4; r++) {
          int row = row0 + quad * 4 + r;
          if (row < NN) {
            float v = acc[t][r] + bbv[t];
            zl[it][(wv * 16 + quad * 4 + r) * 72 + col] = f2bf(v);
            s1a[t] += v; s2a[t] += v * v;
          }
        }
      }
    }
  }
  __syncthreads();                             // lsum/lsq init + cross-wave reduce
#pragma unroll
  for (int t = 0; t < 4; t++) {
    int col = t * 16 + lo;
    atomicAdd(&lsum[col], s1a[t]);
    atomicAdd(&lsq[col], s2a[t]);
  }
  __syncthreads();
  if (tid < 128) {                             // distinct lines per block: no contention
    float v = (tid < 64) ? lsum[tid] : lsq[tid - 64];
    __hip_atomic_store(&pstats[(size_t)blk * 128 + tid], v,
                       __ATOMIC_RELEASE, __HIP_MEMORY_SCOPE_AGENT);
  }
  __syncthreads();                             // all stores issued before arrive

  // ---- device-wide barrier (arrive + spin; counter zeroed per launch) ----
  if (tid == 0) {
    __hip_atomic_fetch_add(bar, 1, __ATOMIC_ACQ_REL, __HIP_MEMORY_SCOPE_AGENT);
    while (__hip_atomic_load(bar, __ATOMIC_ACQUIRE, __HIP_MEMORY_SCOPE_AGENT) < MBLK)
      __builtin_amdgcn_s_sleep(8);
  }
  __syncthreads();

  // ---- reduce 392 partials (L2-resident) + BN coefficients ----
  {
    int c = tid & 127, half = tid >> 7;
    float s = 0.f;
    for (int j = half * 196; j < half * 196 + 196; j++)
      s += __hip_atomic_load(&pstats[(size_t)j * 128 + c],
                             __ATOMIC_RELAXED, __HIP_MEMORY_SCOPE_AGENT);
    red[tid] = s;
  }
  __syncthreads();
  if (tid < 64) {
    float S1 = red[tid] + red[tid + 128];
    float S2 = red[tid + 64] + red[tid + 192];
    float inv = 1.f / (float)NN;
    float mu = S1 * inv;
    float var = S2 * inv - mu * mu;
    float a = gam[tid] * rsqrtf(var + BN_EPS);
    abn[tid] = a;
    cbn[tid] = bet[tid] - mu * a;
  }
  __syncthreads();

  // ---- BN affine + ReLU in place (wave-private rows) ----
#pragma unroll
  for (int it = 0; it < 4; it++) {
#pragma unroll
    for (int h = 0; h < 2; h++) {
      u16x8 zv = *(const u16x8*)(zl[it] + rr * 72 + c0 + h * 8);
      u16x8 o;
#pragma unroll
      for (int m = 0; m < 8; m++) {
        int c = c0 + h * 8 + m;
        o[m] = f2bf(fmaxf(bf2f(zv[m]) * abn[c] + cbn[c], 0.f));
      }
      *(u16x8*)(zl[it] + rr * 72 + c0 + h * 8) = o;
    }
  }

  // ---- phase B: @W2 + b2, epilogue ----
  s16x8 bf2r[2][4];
#pragma unroll
  for (int u = 0; u < 2; u++)
#pragma unroll
    for (int t = 0; t < 4; t++)
      bf2r[u][t] = *(const s16x8*)(wf2 + (size_t)((u * 4 + t) * 64 + lane) * 8);
  float bb2[4];
#pragma unroll
  for (int t = 0; t < 4; t++) bb2[t] = b2[t * 16 + lo];

  if (relu_out) {
#pragma unroll
    for (int it = 0; it < 4; it++) {
      f32x4 acc[4] = {};
#pragma unroll
      for (int u = 0; u < 2; u++) {
        bf16x8 af = *(const bf16x8*)(zl[it] + (wv * 16 + lo) * 72 + u * 32 + quad * 8);
#pragma unroll
        for (int t = 0; t < 4; t++)
          acc[t] = __builtin_amdgcn_mfma_f32_16x16x32_bf16(
              af, __builtin_bit_cast(bf16x8, bf2r[u][t]), acc[t], 0, 0, 0);
      }
#pragma unroll
      for (int t = 0; t < 4; t++) {
        int col = t * 16 + lo;
#pragma unroll
        for (int r = 0; r < 4; r++)
          swb[(wv * 16 + quad * 4 + r) * 72 + col] =
              f2bf(fmaxf(acc[t][r] + bb2[t], 0.f));
      }
      size_t grow = (size_t)blk * 256 + it * 64 + rr;   // same-wave ds order
      if (grow < NN) {
        *(u16x8*)(hb + grow * 64 + c0)     = *(const u16x8*)(swb + rr * 72 + c0);
        *(u16x8*)(hb + grow * 64 + c0 + 8) = *(const u16x8*)(swb + rr * 72 + c0 + 8);
      }
    }
  } else {
    float* outh = out + (size_t)NN * 2;
    float wd0[4], wd1[4];
#pragma unroll
    for (int t = 0; t < 4; t++) {
      wd0[t] = Wd[(t * 16 + lo) * 2];
      wd1[t] = Wd[(t * 16 + lo) * 2 + 1];
    }
    float bd0 = bd[0], bd1 = bd[1];
#pragma unroll
    for (int it = 0; it < 4; it++) {
      f32x4 acc[4] = {};
#pragma unroll
      for (int u = 0; u < 2; u++) {
        bf16x8 af = *(const bf16x8*)(zl[it] + (wv * 16 + lo) * 72 + u * 32 + quad * 8);
#pragma unroll
        for (int t = 0; t < 4; t++)
          acc[t] = __builtin_amdgcn_mfma_f32_16x16x32_bf16(
              af, __builtin_bit_cast(bf16x8, bf2r[u][t]), acc[t], 0, 0, 0);
      }
#pragma unroll
      for (int t = 0; t < 4; t++) {
        int col = t * 16 + lo;
#pragma unroll
        for (int r = 0; r < 4; r++)
          swf[(wv * 16 + quad * 4 + r) * 68 + col] = acc[t][r] + bb2[t];
      }
      int row0 = blk * 256 + it * 64 + wv * 16;
#pragma unroll
      for (int r = 0; r < 4; r++) {
        float p0 = 0.f, p1 = 0.f;
#pragma unroll
        for (int t = 0; t < 4; t++) {
          float v = acc[t][r] + bb2[t];
          p0 += v * wd0[t]; p1 += v * wd1[t];
        }
#pragma unroll
        for (int o = 1; o < 16; o <<= 1) {     // reduce the quad's 16 lanes
          p0 += __shfl_xor(p0, o);
          p1 += __shfl_xor(p1, o);
        }
        int row = row0 + quad * 4 + r;
        if (lo == 0 && row < NN) {
          out[(size_t)row * 2 + 0] = p0 + bd0;
          out[(size_t)row * 2 + 1] = p1 + bd1;
        }
      }
      size_t grow = (size_t)blk * 256 + it * 64 + rr;   // same-wave ds order
      if (grow < NN) {
#pragma unroll
        for (int h = 0; h < 4; h++)
          *(f32x4*)(outh + grow * 64 + c0 + h * 4) =
              *(const f32x4*)(swf + rr * 68 + c0 + h * 4);
      }
    }
  }
}

extern "C" void kernel_launch(void* const* d_in, const int* in_sizes, int n_in,
                              void* d_out, int out_size, void* d_ws, size_t ws_size,
                              hipStream_t stream) {
  (void)in_sizes; (void)n_in; (void)out_size; (void)ws_size;
  const float* x   = (const float*)d_in[0];
  const int*   ei  = (const int*)d_in[1];
  const float* W1s = (const float*)d_in[2];
  const float* b1s = (const float*)d_in[3];
  const float* gms = (const float*)d_in[4];
  const float* bts = (const float*)d_in[5];
  const float* W2s = (const float*)d_in[6];
  const float* b2s = (const float*)d_in[7];
  const float* Wd  = (const float*)d_in[8];
  const float* bd  = (const float*)d_in[9];
  float* out = (float*)d_out;
  const int* src = ei;
  const int* dst = ei + EE;

  char* w = (char*)d_ws;
  size_t off = 0;
  auto alloc = [&](size_t b) { char* p = w + off; off += (b + 255) & ~(size_t)255; return p; };
  ushort_t* aggb   = (ushort_t*)alloc((size_t)NPAD * 64 * 2);   // 12.8 MB (ebuf aliases)
  ushort_t* hb16   = (ushort_t*)alloc((size_t)NPAD * 64 * 2);   // 12.8 MB bf16 rows
  int*      csr    = (int*)alloc((size_t)EE * 4);               // 6.4 MB
  int*      rowptr = (int*)alloc((size_t)(NN + 1) * 4);
  int*      gbc    = (int*)alloc((size_t)NBKT * 4);
  int*      ebase  = (int*)alloc((size_t)NBKT * 4);
  float*    pstats = (float*)alloc((size_t)MBLK * 128 * 4);     // 200 KB partials
  int*      bar    = (int*)alloc(256);                          // per-layer counters
  ushort_t* wf     = (ushort_t*)alloc((size_t)6 * 512 * 8 * 2); // swizzled W frags
  unsigned* ebuf   = (unsigned*)aggb;  // 7.2 MB, dead after k_fine

  hipMemsetAsync(gbc, 0, (size_t)NBKT * 4, stream);
  k_binprep<<<7045, 256, 0, stream>>>(src, dst, gbc, ebuf, x, hb16, W1s, W2s, wf);
  k_bktscan<<<1, 256, 0, stream>>>(gbc, ebase, rowptr, bar);
  k_fine   <<<NBKT, 1024, 0, stream>>>(ebuf, gbc, ebase, rowptr, csr);

  for (int L = 0; L < 3; L++) {
    k_gat<<<(NN + 31) / 32, 256, 0, stream>>>(hb16, rowptr, csr, aggb);
    k_mlp<<<MBLK, 256, 0, stream>>>(aggb, hb16, out,
                                    wf + (size_t)(L * 2) * 4096,
                                    wf + (size_t)(L * 2 + 1) * 4096,
                                    b1s + L * 64, b2s + L * 64,
                                    gms + L * 64, bts + L * 64,
                                    pstats, bar + L, Wd, bd,
                                    (L < 2) ? 1 : 0);
  }
}

// Round 12
// 309.772 us; speedup vs baseline: 1.3092x; 1.3092x over previous
//
#include <hip/hip_runtime.h>

#define NN 100000
#define EE 1600000
#define NPAD 100032          // NN rounded up to 64-row MFMA tiles
#define NBKT 196             // ceil(NN/512) scatter buckets
#define CAP 9216             // bucket capacity (mean 8192, sigma 90 -> 11 sigma)
#define BN_EPS 1e-5f

using f32x4  = __attribute__((ext_vector_type(4))) float;
using f32x8  = __attribute__((ext_vector_type(8))) float;
using s16x8  = __attribute__((ext_vector_type(8))) short;
using u16x4  = __attribute__((ext_vector_type(4))) unsigned short;
using u16x8  = __attribute__((ext_vector_type(8))) unsigned short;
using bf16x8 = __attribute__((ext_vector_type(8))) __bf16;
typedef unsigned short ushort_t;

__device__ __forceinline__ float bf2f(ushort_t b) {
  union { unsigned u; float f; } x; x.u = ((unsigned)b) << 16; return x.f;
}
__device__ __forceinline__ ushort_t f2bf(float f) {
  union { float f; unsigned u; } x; x.f = f;
  unsigned r = x.u + 0x7fffu + ((x.u >> 16) & 1u);   // RN-even; no NaNs in pipeline
  return (ushort_t)(r >> 16);
}

// -------- merged k_bin + k_prep: blocks 0..781 bin (8 edges/thr),
//          782..7031 x->bf16, 7032..7044 W swizzle --------
__global__ __launch_bounds__(256) void k_binprep(
    const int* __restrict__ src, const int* __restrict__ dst,
    int* __restrict__ gbc, unsigned* __restrict__ ebuf,
    const float* __restrict__ x, ushort_t* __restrict__ hb,
    const float* __restrict__ W1s, const float* __restrict__ W2s,
    ushort_t* __restrict__ wf) {
  __shared__ int hist[NBKT];
  int b = blockIdx.x, t = threadIdx.x;
  if (b < 782) {
    for (int i = t; i < NBKT; i += 256) hist[i] = 0;
    __syncthreads();
    int base = b * 2048;
    int s[8], d[8];
#pragma unroll
    for (int j = 0; j < 8; j++) {
      int e = base + j * 256 + t;
      if (e < EE) { s[j] = src[e]; d[j] = dst[e]; atomicAdd(&hist[d[j] >> 9], 1); }
      else d[j] = -1;
    }
    __syncthreads();
    for (int i = t; i < NBKT; i += 256) {
      int c = hist[i];
      hist[i] = c ? atomicAdd(&gbc[i], c) : 0;   // reserve in-bucket run
    }
    __syncthreads();
#pragma unroll
    for (int j = 0; j < 8; j++) {
      if (d[j] >= 0) {
        int bkt = d[j] >> 9;
        int pos = atomicAdd(&hist[bkt], 1);
        if (pos < CAP)
          ebuf[(size_t)bkt * CAP + pos] = (unsigned)s[j] | ((unsigned)(d[j] & 511) << 17);
      }
    }
  } else if (b < 7032) {
    int i = (b - 782) * 256 + t;      // 4 elems of x each
    f32x4 v = *(const f32x4*)(x + (size_t)i * 4);
    u16x4 o;
#pragma unroll
    for (int m = 0; m < 4; m++) o[m] = f2bf(v[m]);
    *(u16x4*)(hb + (size_t)i * 4) = o;
  } else {
    int gid = (b - 7032) * 256 + t;
    if (gid >= 3072) return;          // 6 mats * 2u * 4t * 64 lanes
    int mat = gid >> 9, rem = gid & 511;
    int u = rem >> 8, tt = (rem >> 6) & 3, lane = rem & 63;
    const float* W = ((mat & 1) ? W2s : W1s) + (mat >> 1) * 4096;
    ushort_t* o = wf + gid * 8;
#pragma unroll
    for (int j = 0; j < 8; j++) {
      int k = u * 32 + (lane >> 4) * 8 + j;
      int n = tt * 16 + (lane & 15);
      o[j] = f2bf(W[k * 64 + n]);
    }
  }
}

// scan bucket counts -> ebase; rowptr[NN]=EE; zero BN stats
__global__ void k_bktscan(const int* __restrict__ gbc, int* __restrict__ ebase,
                          int* __restrict__ rowptr, float* __restrict__ stats) {
  __shared__ int sd[256];
  int t = threadIdx.x;
#pragma unroll
  for (int k = 0; k < 3; k++) stats[t + 256 * k] = 0.f;   // 768 floats
  int c = (t < NBKT) ? min(gbc[t], CAP) : 0;
  sd[t] = c; __syncthreads();
  for (int off = 1; off < 256; off <<= 1) {
    int x = 0;
    if (t >= off) x = sd[t - off];
    __syncthreads();
    sd[t] += x;
    __syncthreads();
  }
  if (t < NBKT) ebase[t] = sd[t] - c;          // exclusive
  if (t == NBKT - 1) rowptr[NN] = sd[t];       // == EE
}

// per bucket: LDS degree hist -> scan -> rowptr + fine scatter (1024 thr).
__global__ __launch_bounds__(1024) void k_fine(const unsigned* __restrict__ ebuf,
                                               const int* __restrict__ gbc,
                                               const int* __restrict__ ebase,
                                               int* __restrict__ rowptr,
                                               int* __restrict__ csr) {
  __shared__ int dcur[512];
  __shared__ int sd[256];
  int b = blockIdx.x, t = threadIdx.x;
  int cnt = min(gbc[b], CAP);
  int eb = ebase[b];
  const unsigned* eb_p = ebuf + (size_t)b * CAP;
  if (t < 512) dcur[t] = 0;
  __syncthreads();
  for (int e = t; e < cnt; e += 1024)
    atomicAdd(&dcur[(eb_p[e] >> 17) & 511], 1);
  __syncthreads();
  int a0 = 0, a1 = 0, ps = 0;
  if (t < 256) { a0 = dcur[2 * t]; a1 = dcur[2 * t + 1]; ps = a0 + a1; sd[t] = ps; }
  __syncthreads();
  for (int off = 1; off < 256; off <<= 1) {
    int x = 0;
    if (t < 256 && t >= off) x = sd[t - off];
    __syncthreads();
    if (t < 256) sd[t] += x;
    __syncthreads();
  }
  if (t < 256) {
    int g0 = eb + sd[t] - ps;                  // global csr start for local node 2t
    dcur[2 * t] = g0; dcur[2 * t + 1] = g0 + a0;
    int n = (b << 9) + 2 * t;
    if (n < NN) rowptr[n] = g0;
    if (n + 1 < NN) rowptr[n + 1] = g0 + a0;
  }
  __syncthreads();
  for (int e = t; e < cnt; e += 1024) {
    unsigned v = eb_p[e];
    int pos = atomicAdd(&dcur[(v >> 17) & 511], 1);
    csr[pos] = (int)(v & 0x1FFFFu);
  }
}

// ---------------- k_gat: lean barrier-free gather (proven R8/R9 shape) -------
__global__ __launch_bounds__(256) void k_gat(
    const ushort_t* __restrict__ hb, const int* __restrict__ rowptr,
    const int* __restrict__ csr, ushort_t* __restrict__ aggb) {
  int tid = threadIdx.x;
  int grp = tid >> 3, fl = tid & 7;
  int node = blockIdx.x * 32 + grp;            // grid 3125*32 == NN exactly
  if (node >= NN) return;
  const ushort_t* hbase = hb + fl * 8;
  f32x8 A;
  {
    u16x8 sr = *(const u16x8*)(hbase + (size_t)node * 64);
#pragma unroll
    for (int m = 0; m < 8; m++) A[m] = bf2f(sr[m]);
  }
  int e = rowptr[node];
  int rem = rowptr[node + 1] - e;
  if (rem >= 8) {
    int s0 = csr[e],     s1 = csr[e + 1], s2 = csr[e + 2], s3 = csr[e + 3];
    int s4 = csr[e + 4], s5 = csr[e + 5], s6 = csr[e + 6], s7 = csr[e + 7];
    for (;;) {
      u16x8 r0 = *(const u16x8*)(hbase + (size_t)s0 * 64);
      u16x8 r1 = *(const u16x8*)(hbase + (size_t)s1 * 64);
      u16x8 r2 = *(const u16x8*)(hbase + (size_t)s2 * 64);
      u16x8 r3 = *(const u16x8*)(hbase + (size_t)s3 * 64);
      u16x8 r4 = *(const u16x8*)(hbase + (size_t)s4 * 64);
      u16x8 r5 = *(const u16x8*)(hbase + (size_t)s5 * 64);
      u16x8 r6 = *(const u16x8*)(hbase + (size_t)s6 * 64);
      u16x8 r7 = *(const u16x8*)(hbase + (size_t)s7 * 64);
      e += 8; rem -= 8;
      bool more = (rem >= 8);
      if (more) {                              // prefetch next chunk's indices
        s0 = csr[e];     s1 = csr[e + 1]; s2 = csr[e + 2]; s3 = csr[e + 3];
        s4 = csr[e + 4]; s5 = csr[e + 5]; s6 = csr[e + 6]; s7 = csr[e + 7];
      }
#pragma unroll
      for (int m = 0; m < 8; m++) A[m] += bf2f(r0[m]);
#pragma unroll
      for (int m = 0; m < 8; m++) A[m] += bf2f(r1[m]);
#pragma unroll
      for (int m = 0; m < 8; m++) A[m] += bf2f(r2[m]);
#pragma unroll
      for (int m = 0; m < 8; m++) A[m] += bf2f(r3[m]);
#pragma unroll
      for (int m = 0; m < 8; m++) A[m] += bf2f(r4[m]);
#pragma unroll
      for (int m = 0; m < 8; m++) A[m] += bf2f(r5[m]);
#pragma unroll
      for (int m = 0; m < 8; m++) A[m] += bf2f(r6[m]);
#pragma unroll
      for (int m = 0; m < 8; m++) A[m] += bf2f(r7[m]);
      if (!more) break;
    }
  }
  if (rem > 0) {                               // clamp-masked tail (exact)
    int last = e + rem - 1;
    int s0 = csr[e];
    int s1 = csr[min(e + 1, last)], s2 = csr[min(e + 2, last)];
    int s3 = csr[min(e + 3, last)], s4 = csr[min(e + 4, last)];
    int s5 = csr[min(e + 5, last)], s6 = csr[min(e + 6, last)];
    int s7 = csr[min(e + 7, last)];
    u16x8 r0 = *(const u16x8*)(hbase + (size_t)s0 * 64);
    u16x8 r1 = *(const u16x8*)(hbase + (size_t)s1 * 64);
    u16x8 r2 = *(const u16x8*)(hbase + (size_t)s2 * 64);
    u16x8 r3 = *(const u16x8*)(hbase + (size_t)s3 * 64);
    u16x8 r4 = *(const u16x8*)(hbase + (size_t)s4 * 64);
    u16x8 r5 = *(const u16x8*)(hbase + (size_t)s5 * 64);
    u16x8 r6 = *(const u16x8*)(hbase + (size_t)s6 * 64);
    u16x8 r7 = *(const u16x8*)(hbase + (size_t)s7 * 64);
    float w1 = (rem > 1) ? 1.f : 0.f, w2 = (rem > 2) ? 1.f : 0.f;
    float w3 = (rem > 3) ? 1.f : 0.f, w4 = (rem > 4) ? 1.f : 0.f;
    float w5 = (rem > 5) ? 1.f : 0.f, w6 = (rem > 6) ? 1.f : 0.f;
    float w7 = (rem > 7) ? 1.f : 0.f;
#pragma unroll
    for (int m = 0; m < 8; m++) A[m] += bf2f(r0[m]);
#pragma unroll
    for (int m = 0; m < 8; m++) A[m] += w1 * bf2f(r1[m]);
#pragma unroll
    for (int m = 0; m < 8; m++) A[m] += w2 * bf2f(r2[m]);
#pragma unroll
    for (int m = 0; m < 8; m++) A[m] += w3 * bf2f(r3[m]);
#pragma unroll
    for (int m = 0; m < 8; m++) A[m] += w4 * bf2f(r4[m]);
#pragma unroll
    for (int m = 0; m < 8; m++) A[m] += w5 * bf2f(r5[m]);
#pragma unroll
    for (int m = 0; m < 8; m++) A[m] += w6 * bf2f(r6[m]);
#pragma unroll
    for (int m = 0; m < 8; m++) A[m] += w7 * bf2f(r7[m]);
  }
  u16x8 o;
#pragma unroll
  for (int m = 0; m < 8; m++) o[m] = f2bf(A[m]);
  *(u16x8*)(aggb + (size_t)node * 64 + fl * 8) = o;     // 128B/group coalesced
}

// ---------------- k_mlp1 (R9 proven): 8 tiles/block; stats in regs ----------
__global__ __launch_bounds__(256) void k_mlp1(
    const ushort_t* __restrict__ aggb, ushort_t* __restrict__ zb,
    const ushort_t* __restrict__ wfrag, const float* __restrict__ b1,
    float* __restrict__ stats) {
  __shared__ __align__(16) ushort_t sw[64 * 72];
  __shared__ __align__(16) ushort_t swb[64 * 72];
  __shared__ float lsum[64], lsq[64];
  int tid = threadIdx.x;
  if (tid < 64) lsum[tid] = 0.f;
  else if (tid < 128) lsq[tid - 64] = 0.f;
  int wv = tid >> 6, lane = tid & 63;
  int quad = lane >> 4, lo = lane & 15;
  int rr = tid >> 2, c0 = (tid & 3) * 16;      // staging coords

  s16x8 bfr[2][4];
#pragma unroll
  for (int u = 0; u < 2; u++)
#pragma unroll
    for (int t = 0; t < 4; t++)
      bfr[u][t] = *(const s16x8*)(wfrag + (size_t)((u * 4 + t) * 64 + lane) * 8);
  float bbv[4], s1a[4] = {0.f, 0.f, 0.f, 0.f}, s2a[4] = {0.f, 0.f, 0.f, 0.f};
#pragma unroll
  for (int t = 0; t < 4; t++) bbv[t] = b1[t * 16 + lo];

  for (int it = 0; it < 8; it++) {
    int row0 = blockIdx.x * 512 + it * 64;
    {   // stage tile into sw
      size_t grow = (size_t)row0 + rr;
      u16x8 v0 = {0, 0, 0, 0, 0, 0, 0, 0}, v1 = v0;
      if (grow < NN) {
        v0 = *(const u16x8*)(aggb + grow * 64 + c0);
        v1 = *(const u16x8*)(aggb + grow * 64 + c0 + 8);
      }
      *(u16x8*)(sw + rr * 72 + c0) = v0;
      *(u16x8*)(sw + rr * 72 + c0 + 8) = v1;
    }
    __syncthreads();                           // sw ready; prev zb reads of swb done
    f32x4 acc[4] = {};
#pragma unroll
    for (int u = 0; u < 2; u++) {
      bf16x8 af = *(const bf16x8*)(sw + (wv * 16 + lo) * 72 + u * 32 + quad * 8);
#pragma unroll
      for (int t = 0; t < 4; t++)
        acc[t] = __builtin_amdgcn_mfma_f32_16x16x32_bf16(
            af, __builtin_bit_cast(bf16x8, bfr[u][t]), acc[t], 0, 0, 0);
    }
#pragma unroll
    for (int t = 0; t < 4; t++) {
      int col = t * 16 + lo;
      float s1 = 0.f, s2 = 0.f;
#pragma unroll
      for (int r = 0; r < 4; r++) {
        int row = row0 + quad * 4 + r;
        if (row < NN) {
          float v = acc[t][r] + bbv[t];
          swb[(wv * 16 + quad * 4 + r) * 72 + col] = f2bf(v);
          s1 += v; s2 += v * v;
        }
      }
      s1a[t] += s1; s2a[t] += s2;
    }
    __syncthreads();                           // swb complete
    {
      size_t grow = (size_t)row0 + rr;
      if (grow < NN) {
        *(u16x8*)(zb + grow * 64 + c0)     = *(const u16x8*)(swb + rr * 72 + c0);
        *(u16x8*)(zb + grow * 64 + c0 + 8) = *(const u16x8*)(swb + rr * 72 + c0 + 8);
      }
    }
  }
  // per-block stats reduce: 16 LDS atomics/col, then 128 global atomics/block
#pragma unroll
  for (int t = 0; t < 4; t++) {
    int col = t * 16 + lo;
    atomicAdd(&lsum[col], s1a[t]);
    atomicAdd(&lsq[col], s2a[t]);
  }
  __syncthreads();
  if (tid < 64) {
    atomicAdd(&stats[tid], lsum[tid]);
    atomicAdd(&stats[64 + tid], lsq[tid]);
  }
}

// ---------------- k_mlp2 (v2: blocked like mlp1) ----------------
// 391 blocks x 256 rows (4 tiles of 64). Weight frags + BN coefficients
// loaded ONCE per block; double-buffered LDS (sw stage / swb|swf epilogue),
// 2 barriers per tile (mlp1's proven pattern). relu_out=1: hb16 = relu(...).
// relu_out=0: h -> out+200000 (fp32) + fused decoder out = h@Wd + bd.
__global__ __launch_bounds__(256) void k_mlp2(
    const ushort_t* __restrict__ zb, const float* __restrict__ stats,
    const float* __restrict__ gamma, const float* __restrict__ beta,
    const ushort_t* __restrict__ wfrag, const float* __restrict__ b2,
    ushort_t* __restrict__ hb, float* __restrict__ out,
    const float* __restrict__ Wd, const float* __restrict__ bd, int relu_out) {
  __shared__ __align__(16) ushort_t sw[64 * 72];
  __shared__ __align__(16) ushort_t swb[64 * 72];
  __shared__ __align__(16) float swf[64 * 68];     // f32 restage (decoder path)
  __shared__ float abn[64], cbn[64];
  int tid = threadIdx.x;
  if (tid < 64) {   // fused BN finalize (once per block)
    float inv = 1.f / (float)NN;
    float mu = stats[tid] * inv;
    float var = stats[64 + tid] * inv - mu * mu;
    float a = gamma[tid] * rsqrtf(var + BN_EPS);
    abn[tid] = a;
    cbn[tid] = beta[tid] - mu * a;
  }
  int wv = tid >> 6, lane = tid & 63;
  int quad = lane >> 4, lo = lane & 15;
  int rr = tid >> 2, c0 = (tid & 3) * 16;

  s16x8 bfr[2][4];
#pragma unroll
  for (int u = 0; u < 2; u++)
#pragma unroll
    for (int t = 0; t < 4; t++)
      bfr[u][t] = *(const s16x8*)(wfrag + (size_t)((u * 4 + t) * 64 + lane) * 8);
  float bbv[4];
#pragma unroll
  for (int t = 0; t < 4; t++) bbv[t] = b2[t * 16 + lo];
  float wd0[4], wd1[4], bd0 = 0.f, bd1 = 0.f;
  if (!relu_out) {
#pragma unroll
    for (int t = 0; t < 4; t++) {
      wd0[t] = Wd[(t * 16 + lo) * 2];
      wd1[t] = Wd[(t * 16 + lo) * 2 + 1];
    }
    bd0 = bd[0]; bd1 = bd[1];
  }
  __syncthreads();                             // abn/cbn ready

  float* outh = out + (size_t)NN * 2;
  for (int it = 0; it < 4; it++) {
    int row0 = blockIdx.x * 256 + it * 64;
    {   // stage: zb -> BN affine + ReLU -> bf16 tile in sw
      size_t grow = (size_t)row0 + rr;
      u16x8 zv0 = {0, 0, 0, 0, 0, 0, 0, 0}, zv1 = zv0;
      if (grow < NN) {
        zv0 = *(const u16x8*)(zb + grow * 64 + c0);
        zv1 = *(const u16x8*)(zb + grow * 64 + c0 + 8);
      }
      u16x8 o0, o1;
#pragma unroll
      for (int m = 0; m < 8; m++) {
        o0[m] = f2bf(fmaxf(bf2f(zv0[m]) * abn[c0 + m] + cbn[c0 + m], 0.f));
        o1[m] = f2bf(fmaxf(bf2f(zv1[m]) * abn[c0 + 8 + m] + cbn[c0 + 8 + m], 0.f));
      }
      *(u16x8*)(sw + rr * 72 + c0) = o0;
      *(u16x8*)(sw + rr * 72 + c0 + 8) = o1;
    }
    __syncthreads();                           // sw ready; prev-tile store reads done
    f32x4 acc[4] = {};
#pragma unroll
    for (int u = 0; u < 2; u++) {
      bf16x8 af = *(const bf16x8*)(sw + (wv * 16 + lo) * 72 + u * 32 + quad * 8);
#pragma unroll
      for (int t = 0; t < 4; t++)
        acc[t] = __builtin_amdgcn_mfma_f32_16x16x32_bf16(
            af, __builtin_bit_cast(bf16x8, bfr[u][t]), acc[t], 0, 0, 0);
    }
    if (relu_out) {
#pragma unroll
      for (int t = 0; t < 4; t++) {
        int col = t * 16 + lo;
#pragma unroll
        for (int r = 0; r < 4; r++)
          swb[(wv * 16 + quad * 4 + r) * 72 + col] =
              f2bf(fmaxf(acc[t][r] + bbv[t], 0.f));
      }
      __syncthreads();                         // swb complete
      size_t grow = (size_t)row0 + rr;
      if (grow < NN) {
        *(u16x8*)(hb + grow * 64 + c0)     = *(const u16x8*)(swb + rr * 72 + c0);
        *(u16x8*)(hb + grow * 64 + c0 + 8) = *(const u16x8*)(swb + rr * 72 + c0 + 8);
      }
    } else {
#pragma unroll
      for (int t = 0; t < 4; t++) {
        int col = t * 16 + lo;
#pragma unroll
        for (int r = 0; r < 4; r++)
          swf[(wv * 16 + quad * 4 + r) * 68 + col] = acc[t][r] + bbv[t];
      }
#pragma unroll
      for (int r = 0; r < 4; r++) {            // fused decoder (2 cols)
        float p0 = 0.f, p1 = 0.f;
#pragma unroll
        for (int t = 0; t < 4; t++) {
          float v = acc[t][r] + bbv[t];
          p0 += v * wd0[t]; p1 += v * wd1[t];
        }
#pragma unroll
        for (int o = 1; o < 16; o <<= 1) {     // reduce the quad's 16 lanes
          p0 += __shfl_xor(p0, o);
          p1 += __shfl_xor(p1, o);
        }
        int row = row0 + wv * 16 + quad * 4 + r;
        if (lo == 0 && row < NN) {
          out[(size_t)row * 2 + 0] = p0 + bd0;
          out[(size_t)row * 2 + 1] = p1 + bd1;
        }
      }
      __syncthreads();                         // swf complete
      size_t grow = (size_t)row0 + rr;
      if (grow < NN) {
#pragma unroll
        for (int h = 0; h < 4; h++)
          *(f32x4*)(outh + grow * 64 + c0 + h * 4) =
              *(const f32x4*)(swf + rr * 68 + c0 + h * 4);
      }
    }
  }
}

extern "C" void kernel_launch(void* const* d_in, const int* in_sizes, int n_in,
                              void* d_out, int out_size, void* d_ws, size_t ws_size,
                              hipStream_t stream) {
  (void)in_sizes; (void)n_in; (void)out_size; (void)ws_size;
  const float* x   = (const float*)d_in[0];
  const int*   ei  = (const int*)d_in[1];
  const float* W1s = (const float*)d_in[2];
  const float* b1s = (const float*)d_in[3];
  const float* gms = (const float*)d_in[4];
  const float* bts = (const float*)d_in[5];
  const float* W2s = (const float*)d_in[6];
  const float* b2s = (const float*)d_in[7];
  const float* Wd  = (const float*)d_in[8];
  const float* bd  = (const float*)d_in[9];
  float* out = (float*)d_out;
  const int* src = ei;
  const int* dst = ei + EE;

  char* w = (char*)d_ws;
  size_t off = 0;
  auto alloc = [&](size_t b) { char* p = w + off; off += (b + 255) & ~(size_t)255; return p; };
  ushort_t* zb     = (ushort_t*)alloc((size_t)NPAD * 64 * 2);   // 12.8 MB (ebuf aliases)
  ushort_t* aggb   = (ushort_t*)alloc((size_t)NPAD * 64 * 2);   // 12.8 MB bf16 aggregates
  ushort_t* hb16   = (ushort_t*)alloc((size_t)NPAD * 64 * 2);   // 12.8 MB bf16 rows
  int*      csr    = (int*)alloc((size_t)EE * 4);               // 6.4 MB
  int*      rowptr = (int*)alloc((size_t)(NN + 1) * 4);
  int*      gbc    = (int*)alloc((size_t)NBKT * 4);
  int*      ebase  = (int*)alloc((size_t)NBKT * 4);
  float*    stats  = (float*)alloc(768 * 4);                    // 3 x [sum|sq|spare]
  ushort_t* wf     = (ushort_t*)alloc((size_t)6 * 512 * 8 * 2); // swizzled W frags
  unsigned* ebuf   = (unsigned*)zb;  // 196*9216*4 = 7.2 MB, used pre-mlp only

  hipMemsetAsync(gbc, 0, (size_t)NBKT * 4, stream);
  k_binprep<<<7045, 256, 0, stream>>>(src, dst, gbc, ebuf, x, hb16, W1s, W2s, wf);
  k_bktscan<<<1, 256, 0, stream>>>(gbc, ebase, rowptr, stats);
  k_fine   <<<NBKT, 1024, 0, stream>>>(ebuf, gbc, ebase, rowptr, csr);

  int nblk2 = (NN + 255) / 256;     // 391
  for (int L = 0; L < 3; L++) {
    k_gat <<<(NN + 31) / 32, 256, 0, stream>>>(hb16, rowptr, csr, aggb);
    k_mlp1<<<NBKT, 256, 0, stream>>>(aggb, zb,
                                     wf + (size_t)(L * 2) * 4096,
                                     b1s + L * 64, stats + L * 256);
    k_mlp2<<<nblk2, 256, 0, stream>>>(zb, stats + L * 256,
                                      gms + L * 64, bts + L * 64,
                                      wf + (size_t)(L * 2 + 1) * 4096,
                                      b2s + L * 64, hb16, out, Wd, bd,
                                      (L < 2) ? 1 : 0);
  }
}